// Round 2
// baseline (2272.949 us; speedup 1.0000x reference)
//
#include <hip/hip_runtime.h>
#include <stdint.h>

// RWKV TimeMixing on gfx950. I/O dtype: float32 (per reference).
// Internal: bf16 for MFMA GEMMs, f32 for the WKV scan state.
// Workspace layout (200 MiB):
//   [0,32M)     mixbuf bf16 (reused as rwkv)
//   [32M,96M)   key   f32
//   [96M,160M)  value f32
//   [160M,192M) rsig  bf16 (sigmoid(receptance))
//   [192M,200M) wk/wv/wr/wo bf16 (2 MiB each)

using bf16x8 = __attribute__((ext_vector_type(8))) __bf16;
using f32x4  = __attribute__((ext_vector_type(4))) float;

union FU { float f; unsigned int u; };

__device__ __forceinline__ unsigned short f2b(float f) {
  FU v; v.f = f;
  unsigned int u = v.u;
  return (unsigned short)((u + 0x7fffu + ((u >> 16) & 1u)) >> 16);
}
__device__ __forceinline__ float b2f(unsigned short h) {
  FU v; v.u = ((unsigned int)h) << 16; return v.f;
}

// ---------------- weight f32 -> bf16 convert (4 matrices of 1M elems) -----
__global__ __launch_bounds__(256) void wconv_kernel(
    const float* __restrict__ w0, const float* __restrict__ w1,
    const float* __restrict__ w2, const float* __restrict__ w3,
    unsigned short* __restrict__ o0, unsigned short* __restrict__ o1,
    unsigned short* __restrict__ o2, unsigned short* __restrict__ o3)
{
  int b = blockIdx.x;            // 4096 blocks; 1024 per matrix
  int mat = b >> 10, blk = b & 1023;
  const float* src = (mat == 0) ? w0 : (mat == 1) ? w1 : (mat == 2) ? w2 : w3;
  unsigned short* dst = (mat == 0) ? o0 : (mat == 1) ? o1 : (mat == 2) ? o2 : o3;
  int i = blk * 1024 + threadIdx.x * 4;
  float4 v = *(const float4*)(src + i);
  union { int2 i2; unsigned short u[4]; } o;
  o.u[0] = f2b(v.x); o.u[1] = f2b(v.y); o.u[2] = f2b(v.z); o.u[3] = f2b(v.w);
  *(int2*)(dst + i) = o.i2;
}

// ---------------- mix: out = bf16(x*m + prev_x*(1-m)) ----------------
__global__ __launch_bounds__(256) void mix_kernel(
    const float* __restrict__ x, const float* __restrict__ mix,
    unsigned short* __restrict__ out, int T, int C)
{
  int i = blockIdx.x * 256 + threadIdx.x;
  int base = i * 8;
  int row = base / C;          // b*T + t
  int t = row - (row / T) * T; // t within batch
  int c = base - row * C;
  float4 x0 = *(const float4*)(x + base);
  float4 x1 = *(const float4*)(x + base + 4);
  float4 p0 = make_float4(0.f, 0.f, 0.f, 0.f), p1 = p0;
  if (t > 0) {
    p0 = *(const float4*)(x + base - C);
    p1 = *(const float4*)(x + base - C + 4);
  }
  float4 m0 = *(const float4*)(mix + c);
  float4 m1 = *(const float4*)(mix + c + 4);
  union { int4 i4; unsigned short u[8]; } o;
  o.u[0] = f2b(x0.x * m0.x + p0.x * (1.f - m0.x));
  o.u[1] = f2b(x0.y * m0.y + p0.y * (1.f - m0.y));
  o.u[2] = f2b(x0.z * m0.z + p0.z * (1.f - m0.z));
  o.u[3] = f2b(x0.w * m0.w + p0.w * (1.f - m0.w));
  o.u[4] = f2b(x1.x * m1.x + p1.x * (1.f - m1.x));
  o.u[5] = f2b(x1.y * m1.y + p1.y * (1.f - m1.y));
  o.u[6] = f2b(x1.z * m1.z + p1.z * (1.f - m1.z));
  o.u[7] = f2b(x1.w * m1.w + p1.w * (1.f - m1.w));
  *(int4*)(out + base) = o.i4;
}

// ---------------- GEMM: out[m,n] = sum_k A[m,k]*W[n,k] ----------------
// A [M,K] bf16 row-major, W [N,K] bf16 row-major. 128x128 tile, BK=32,
// 256 threads = 4 waves in 2x2, each wave 4x4 tiles of mfma 16x16x32 bf16.
#define GM_F32 0   // float* out
#define GM_SIG 1   // bf16 sigmoid out

template<int MODE>
__global__ __launch_bounds__(256) void gemm_bt(
    const unsigned short* __restrict__ A,
    const unsigned short* __restrict__ W,
    void* __restrict__ outp, int M, int N, int K)
{
  __shared__ __align__(16) unsigned short As[128 * 32];
  __shared__ __align__(16) unsigned short Bs[128 * 32];
  const int tid  = threadIdx.x;
  const int lane = tid & 63;
  const int w    = tid >> 6;
  const int wm   = w >> 1, wn = w & 1;
  const int col  = lane & 15, quad = lane >> 4;
  const int mBlk = blockIdx.x * 128, nBlk = blockIdx.y * 128;

  const int r0 = tid >> 2;            // 0..63
  const int r1 = r0 + 64;             // 64..127
  const int koff = (tid & 3) * 8;     // bf16 elems

  const f32x4 zero = {0.f, 0.f, 0.f, 0.f};
  f32x4 acc[4][4];
#pragma unroll
  for (int i = 0; i < 4; ++i)
#pragma unroll
    for (int j = 0; j < 4; ++j) acc[i][j] = zero;

  const unsigned short* Ab = A + (size_t)mBlk * K;
  const unsigned short* Wb = W + (size_t)nBlk * K;

  for (int k0 = 0; k0 < K; k0 += 32) {
    *(int4*)&As[r0 * 32 + koff] = *(const int4*)(Ab + r0 * K + k0 + koff);
    *(int4*)&As[r1 * 32 + koff] = *(const int4*)(Ab + r1 * K + k0 + koff);
    *(int4*)&Bs[r0 * 32 + koff] = *(const int4*)(Wb + r0 * K + k0 + koff);
    *(int4*)&Bs[r1 * 32 + koff] = *(const int4*)(Wb + r1 * K + k0 + koff);
    __syncthreads();

    bf16x8 af[4], bg[4];
#pragma unroll
    for (int i = 0; i < 4; ++i)
      af[i] = *(const bf16x8*)&As[(wm * 64 + i * 16 + col) * 32 + quad * 8];
#pragma unroll
    for (int j = 0; j < 4; ++j)
      bg[j] = *(const bf16x8*)&Bs[(wn * 64 + j * 16 + col) * 32 + quad * 8];
#pragma unroll
    for (int i = 0; i < 4; ++i)
#pragma unroll
      for (int j = 0; j < 4; ++j)
        acc[i][j] = __builtin_amdgcn_mfma_f32_16x16x32_bf16(af[i], bg[j], acc[i][j], 0, 0, 0);

    __syncthreads();
  }

  // epilogue: C/D layout col=lane&15, row=quad*4+reg (m89/m91-verified)
  const int mBase = mBlk + wm * 64, nBase = nBlk + wn * 64;
#pragma unroll
  for (int i = 0; i < 4; ++i) {
#pragma unroll
    for (int j = 0; j < 4; ++j) {
#pragma unroll
      for (int r = 0; r < 4; ++r) {
        int rg = mBase + i * 16 + quad * 4 + r;
        int cg = nBase + j * 16 + col;
        float v = acc[i][j][r];
        if (MODE == GM_F32) {
          ((float*)outp)[(size_t)rg * N + cg] = v;
        } else {
          float s = 1.0f / (1.0f + __expf(-v));
          ((unsigned short*)outp)[(size_t)rg * N + cg] = f2b(s);
        }
      }
    }
  }
}

// ---------------- WKV scan: one thread per (b,c), chunked prefetch -------
__global__ __launch_bounds__(256) void wkv_kernel(
    const float* __restrict__ key, const float* __restrict__ value,
    const unsigned short* __restrict__ rsig,
    const float* __restrict__ td, const float* __restrict__ tf,
    unsigned short* __restrict__ rwkv, int T, int C)
{
  int tid = blockIdx.x * 256 + threadIdx.x;  // 0..B*C-1
  int b = tid / C;
  int c = tid - b * C;
  float w = -__expf(td[c]);
  float u = tf[c];
  float num = 0.f, den = 0.f, mx = -1e38f;
  size_t base = (size_t)b * T * C + c;

  const int D = 8;
  float kq[2][D], vq[2][D];
  unsigned short rq[2][D];
#pragma unroll
  for (int j = 0; j < D; ++j) {
    kq[0][j] = key[base + (size_t)j * C];
    vq[0][j] = value[base + (size_t)j * C];
    rq[0][j] = rsig[base + (size_t)j * C];
  }
  int cur = 0;
  for (int t0 = 0; t0 < T; t0 += D) {
    int nxt = cur ^ 1;
    if (t0 + D < T) {
      size_t nb = base + (size_t)(t0 + D) * C;
#pragma unroll
      for (int j = 0; j < D; ++j) {
        kq[nxt][j] = key[nb + (size_t)j * C];
        vq[nxt][j] = value[nb + (size_t)j * C];
        rq[nxt][j] = rsig[nb + (size_t)j * C];
      }
    }
#pragma unroll
    for (int j = 0; j < D; ++j) {
      float k = kq[cur][j], v = vq[cur][j];
      float ku = k + u;
      float mo = fmaxf(mx, ku);
      float e1 = __expf(mx - mo);
      float e2 = __expf(ku - mo);
      float o = (e1 * num + e2 * v) / (e1 * den + e2);
      float r = b2f(rq[cur][j]);
      rwkv[base + (size_t)(t0 + j) * C] = f2b(r * o);
      float mw = mx + w;
      float ms = fmaxf(mw, k);
      float s1 = __expf(mw - ms);
      float s2 = __expf(k - ms);
      num = s1 * num + s2 * v;
      den = s1 * den + s2;
      mx = ms;
    }
    cur = nxt;
  }
}

extern "C" void kernel_launch(void* const* d_in, const int* in_sizes, int n_in,
                              void* d_out, int out_size, void* d_ws, size_t ws_size,
                              hipStream_t stream)
{
  const float* x  = (const float*)d_in[0];
  const float* wk = (const float*)d_in[1];
  const float* wv = (const float*)d_in[2];
  const float* wr = (const float*)d_in[3];
  const float* wo = (const float*)d_in[4];
  const float* td = (const float*)d_in[5];
  const float* tf = (const float*)d_in[6];
  const float* mk = (const float*)d_in[7];
  const float* mv = (const float*)d_in[8];
  const float* mr = (const float*)d_in[9];

  const int B = 8, T = 2048, C = 1024;
  const int M = B * T;  // 16384
  const size_t MB = 1024 * 1024;

  char* ws = (char*)d_ws;
  unsigned short* mixbuf = (unsigned short*)(ws);              // 32 MiB
  float*          keyf   = (float*)(ws + 32 * MB);             // 64 MiB
  float*          valf   = (float*)(ws + 96 * MB);             // 64 MiB
  unsigned short* rsig   = (unsigned short*)(ws + 160 * MB);   // 32 MiB
  unsigned short* wkb    = (unsigned short*)(ws + 192 * MB);   // 2 MiB each
  unsigned short* wvb    = (unsigned short*)(ws + 194 * MB);
  unsigned short* wrb    = (unsigned short*)(ws + 196 * MB);
  unsigned short* wob    = (unsigned short*)(ws + 198 * MB);
  unsigned short* rwkv   = mixbuf;  // mixbuf dead by the time wkv runs

  dim3 gGemm(M / 128, C / 128);
  int mixBlocks = (M * C / 8) / 256;

  wconv_kernel<<<4096, 256, 0, stream>>>(wk, wv, wr, wo, wkb, wvb, wrb, wob);
  mix_kernel<<<mixBlocks, 256, 0, stream>>>(x, mk, mixbuf, T, C);
  gemm_bt<GM_F32><<<gGemm, 256, 0, stream>>>(mixbuf, wkb, keyf, M, C, C);
  mix_kernel<<<mixBlocks, 256, 0, stream>>>(x, mv, mixbuf, T, C);
  gemm_bt<GM_F32><<<gGemm, 256, 0, stream>>>(mixbuf, wvb, valf, M, C, C);
  mix_kernel<<<mixBlocks, 256, 0, stream>>>(x, mr, mixbuf, T, C);
  gemm_bt<GM_SIG><<<gGemm, 256, 0, stream>>>(mixbuf, wrb, rsig, M, C, C);
  wkv_kernel<<<(B * C) / 256, 256, 0, stream>>>(keyf, valf, rsig, td, tf, rwkv, T, C);
  gemm_bt<GM_F32><<<gGemm, 256, 0, stream>>>(rwkv, wob, (float*)d_out, M, C, C);
}

// Round 3
// 457.040 us; speedup vs baseline: 4.9732x; 4.9732x over previous
//
#include <hip/hip_runtime.h>
#include <stdint.h>

// RWKV TimeMixing on gfx950. I/O dtype: float32 (per reference).
// Internal: bf16 for MFMA GEMMs + k/v/rsig storage, f32 for WKV scan state.
// WKV scan parallelized over T: chunked associative scan (NC=32 chunks of L=64).
// Workspace layout (142 MiB):
//   [0,32M)     mixbuf bf16 (reused as rwkv)
//   [32M,64M)   kb  bf16
//   [64M,96M)   vb  bf16
//   [96M,128M)  rsig bf16 (sigmoid(receptance))
//   [128M,136M) wk/wv/wr/wo bf16 (2 MiB each)
//   [136M,142M) scan scratch: snum,sden,smx,inum,iden,imx (1 MiB each)

using bf16x8 = __attribute__((ext_vector_type(8))) __bf16;
using f32x4  = __attribute__((ext_vector_type(4))) float;

union FU { float f; unsigned int u; };

__device__ __forceinline__ unsigned short f2b(float f) {
  FU v; v.f = f;
  unsigned int u = v.u;
  return (unsigned short)((u + 0x7fffu + ((u >> 16) & 1u)) >> 16);
}
__device__ __forceinline__ float b2f(unsigned short h) {
  FU v; v.u = ((unsigned int)h) << 16; return v.f;
}

// ---------------- weight f32 -> bf16 convert (4 matrices of 1M elems) -----
__global__ __launch_bounds__(256) void wconv_kernel(
    const float* __restrict__ w0, const float* __restrict__ w1,
    const float* __restrict__ w2, const float* __restrict__ w3,
    unsigned short* __restrict__ o0, unsigned short* __restrict__ o1,
    unsigned short* __restrict__ o2, unsigned short* __restrict__ o3)
{
  int b = blockIdx.x;            // 4096 blocks; 1024 per matrix
  int mat = b >> 10, blk = b & 1023;
  const float* src = (mat == 0) ? w0 : (mat == 1) ? w1 : (mat == 2) ? w2 : w3;
  unsigned short* dst = (mat == 0) ? o0 : (mat == 1) ? o1 : (mat == 2) ? o2 : o3;
  int i = blk * 1024 + threadIdx.x * 4;
  float4 v = *(const float4*)(src + i);
  union { int2 i2; unsigned short u[4]; } o;
  o.u[0] = f2b(v.x); o.u[1] = f2b(v.y); o.u[2] = f2b(v.z); o.u[3] = f2b(v.w);
  *(int2*)(dst + i) = o.i2;
}

// ---------------- mix: out = bf16(x*m + prev_x*(1-m)) ----------------
__global__ __launch_bounds__(256) void mix_kernel(
    const float* __restrict__ x, const float* __restrict__ mix,
    unsigned short* __restrict__ out, int T, int C)
{
  int i = blockIdx.x * 256 + threadIdx.x;
  int base = i * 8;
  int row = base / C;          // b*T + t
  int t = row - (row / T) * T; // t within batch
  int c = base - row * C;
  float4 x0 = *(const float4*)(x + base);
  float4 x1 = *(const float4*)(x + base + 4);
  float4 p0 = make_float4(0.f, 0.f, 0.f, 0.f), p1 = p0;
  if (t > 0) {
    p0 = *(const float4*)(x + base - C);
    p1 = *(const float4*)(x + base - C + 4);
  }
  float4 m0 = *(const float4*)(mix + c);
  float4 m1 = *(const float4*)(mix + c + 4);
  union { int4 i4; unsigned short u[8]; } o;
  o.u[0] = f2b(x0.x * m0.x + p0.x * (1.f - m0.x));
  o.u[1] = f2b(x0.y * m0.y + p0.y * (1.f - m0.y));
  o.u[2] = f2b(x0.z * m0.z + p0.z * (1.f - m0.z));
  o.u[3] = f2b(x0.w * m0.w + p0.w * (1.f - m0.w));
  o.u[4] = f2b(x1.x * m1.x + p1.x * (1.f - m1.x));
  o.u[5] = f2b(x1.y * m1.y + p1.y * (1.f - m1.y));
  o.u[6] = f2b(x1.z * m1.z + p1.z * (1.f - m1.z));
  o.u[7] = f2b(x1.w * m1.w + p1.w * (1.f - m1.w));
  *(int4*)(out + base) = o.i4;
}

// ---------------- GEMM: out[m,n] = sum_k A[m,k]*W[n,k] ----------------
#define GM_F32 0   // float* out
#define GM_SIG 1   // bf16 sigmoid out
#define GM_B16 2   // bf16 out

template<int MODE>
__global__ __launch_bounds__(256) void gemm_bt(
    const unsigned short* __restrict__ A,
    const unsigned short* __restrict__ W,
    void* __restrict__ outp, int M, int N, int K)
{
  __shared__ __align__(16) unsigned short As[128 * 32];
  __shared__ __align__(16) unsigned short Bs[128 * 32];
  const int tid  = threadIdx.x;
  const int lane = tid & 63;
  const int w    = tid >> 6;
  const int wm   = w >> 1, wn = w & 1;
  const int col  = lane & 15, quad = lane >> 4;
  const int mBlk = blockIdx.x * 128, nBlk = blockIdx.y * 128;

  const int r0 = tid >> 2;            // 0..63
  const int r1 = r0 + 64;             // 64..127
  const int koff = (tid & 3) * 8;     // bf16 elems

  const f32x4 zero = {0.f, 0.f, 0.f, 0.f};
  f32x4 acc[4][4];
#pragma unroll
  for (int i = 0; i < 4; ++i)
#pragma unroll
    for (int j = 0; j < 4; ++j) acc[i][j] = zero;

  const unsigned short* Ab = A + (size_t)mBlk * K;
  const unsigned short* Wb = W + (size_t)nBlk * K;

  for (int k0 = 0; k0 < K; k0 += 32) {
    *(int4*)&As[r0 * 32 + koff] = *(const int4*)(Ab + r0 * K + k0 + koff);
    *(int4*)&As[r1 * 32 + koff] = *(const int4*)(Ab + r1 * K + k0 + koff);
    *(int4*)&Bs[r0 * 32 + koff] = *(const int4*)(Wb + r0 * K + k0 + koff);
    *(int4*)&Bs[r1 * 32 + koff] = *(const int4*)(Wb + r1 * K + k0 + koff);
    __syncthreads();

    bf16x8 af[4], bg[4];
#pragma unroll
    for (int i = 0; i < 4; ++i)
      af[i] = *(const bf16x8*)&As[(wm * 64 + i * 16 + col) * 32 + quad * 8];
#pragma unroll
    for (int j = 0; j < 4; ++j)
      bg[j] = *(const bf16x8*)&Bs[(wn * 64 + j * 16 + col) * 32 + quad * 8];
#pragma unroll
    for (int i = 0; i < 4; ++i)
#pragma unroll
      for (int j = 0; j < 4; ++j)
        acc[i][j] = __builtin_amdgcn_mfma_f32_16x16x32_bf16(af[i], bg[j], acc[i][j], 0, 0, 0);

    __syncthreads();
  }

  // epilogue: C/D layout col=lane&15, row=quad*4+reg (m89/m91-verified)
  const int mBase = mBlk + wm * 64, nBase = nBlk + wn * 64;
#pragma unroll
  for (int i = 0; i < 4; ++i) {
#pragma unroll
    for (int j = 0; j < 4; ++j) {
#pragma unroll
      for (int r = 0; r < 4; ++r) {
        int rg = mBase + i * 16 + quad * 4 + r;
        int cg = nBase + j * 16 + col;
        float v = acc[i][j][r];
        if (MODE == GM_F32) {
          ((float*)outp)[(size_t)rg * N + cg] = v;
        } else if (MODE == GM_SIG) {
          float s = 1.0f / (1.0f + __expf(-v));
          ((unsigned short*)outp)[(size_t)rg * N + cg] = f2b(s);
        } else {
          ((unsigned short*)outp)[(size_t)rg * N + cg] = f2b(v);
        }
      }
    }
  }
}

// ---------------- WKV chunked scan ----------------
// Unnormalized recurrence: U_t = e^w U_{t-1} + e^{k_t} v_t (num), same for den.
// Stabilized triple (num, den, mx) represents (num*e^mx, den*e^mx).
// NC=32 chunks of L=64 over T=2048; B*C=8192 series.

// pass1: per-chunk local scan from zero state -> summary triple.
__global__ __launch_bounds__(256) void wkv_pass1(
    const unsigned short* __restrict__ kb, const unsigned short* __restrict__ vb,
    const float* __restrict__ td,
    float* __restrict__ snum, float* __restrict__ sden, float* __restrict__ smx,
    int T, int C, int L)
{
  int g = blockIdx.x * 256 + threadIdx.x;  // 0..B*C*NC-1
  int bc = g & 8191;
  int ch = g >> 13;
  int c = bc & 1023;
  float w = -__expf(td[c]);
  float num = 0.f, den = 0.f, mx = -1e38f;
  size_t base = ((size_t)(bc >> 10) * T + (size_t)ch * L) * C + c;
  for (int j0 = 0; j0 < L; j0 += 8) {
    float kq[8], vq[8];
#pragma unroll
    for (int j = 0; j < 8; ++j) {
      size_t a = base + (size_t)(j0 + j) * C;
      kq[j] = b2f(kb[a]);
      vq[j] = b2f(vb[a]);
    }
#pragma unroll
    for (int j = 0; j < 8; ++j) {
      float k = kq[j], v = vq[j];
      float mw = mx + w;
      float ms = fmaxf(mw, k);
      float s1 = __expf(mw - ms);
      float s2 = __expf(k - ms);
      num = s1 * num + s2 * v;
      den = s1 * den + s2;
      mx = ms;
    }
  }
  int idx = ch * 8192 + bc;
  snum[idx] = num; sden[idx] = den; smx[idx] = mx;
}

// pass2: sequential scan over NC=32 chunk summaries per series; writes the
// INCOMING state for each chunk.
__global__ __launch_bounds__(64) void wkv_pass2(
    const float* __restrict__ snum, const float* __restrict__ sden,
    const float* __restrict__ smx, const float* __restrict__ td,
    float* __restrict__ inum, float* __restrict__ iden, float* __restrict__ imx,
    int L)
{
  int bc = blockIdx.x * 64 + threadIdx.x;  // 0..8191
  int c = bc & 1023;
  float Wl = -__expf(td[c]) * (float)L;
  float num = 0.f, den = 0.f, mx = -1e38f;
#pragma unroll
  for (int ch = 0; ch < 32; ++ch) {
    int idx = ch * 8192 + bc;
    inum[idx] = num; iden[idx] = den; imx[idx] = mx;
    float sn = snum[idx], sd = sden[idx], sm = smx[idx];
    float mi = mx + Wl;
    float mo = fmaxf(mi, sm);
    float e1 = __expf(mi - mo);
    float e2 = __expf(sm - mo);
    num = e1 * num + e2 * sn;
    den = e1 * den + e2 * sd;
    mx = mo;
  }
}

// pass3: re-scan each chunk seeded with incoming state, emit rwkv outputs.
__global__ __launch_bounds__(256) void wkv_pass3(
    const unsigned short* __restrict__ kb, const unsigned short* __restrict__ vb,
    const unsigned short* __restrict__ rsig,
    const float* __restrict__ td, const float* __restrict__ tf,
    const float* __restrict__ inum, const float* __restrict__ iden,
    const float* __restrict__ imx,
    unsigned short* __restrict__ rwkv, int T, int C, int L)
{
  int g = blockIdx.x * 256 + threadIdx.x;
  int bc = g & 8191;
  int ch = g >> 13;
  int c = bc & 1023;
  float w = -__expf(td[c]);
  float u = tf[c];
  int idx = ch * 8192 + bc;
  float num = inum[idx], den = iden[idx], mx = imx[idx];
  size_t base = ((size_t)(bc >> 10) * T + (size_t)ch * L) * C + c;
  for (int j0 = 0; j0 < L; j0 += 8) {
    float kq[8], vq[8], rq[8];
#pragma unroll
    for (int j = 0; j < 8; ++j) {
      size_t a = base + (size_t)(j0 + j) * C;
      kq[j] = b2f(kb[a]);
      vq[j] = b2f(vb[a]);
      rq[j] = b2f(rsig[a]);
    }
#pragma unroll
    for (int j = 0; j < 8; ++j) {
      float k = kq[j], v = vq[j];
      float ku = k + u;
      float mo = fmaxf(mx, ku);
      float e1 = __expf(mx - mo);
      float e2 = __expf(ku - mo);
      float o = (e1 * num + e2 * v) / (e1 * den + e2);
      rwkv[base + (size_t)(j0 + j) * C] = f2b(rq[j] * o);
      float mw = mx + w;
      float ms = fmaxf(mw, k);
      float s1 = __expf(mw - ms);
      float s2 = __expf(k - ms);
      num = s1 * num + s2 * v;
      den = s1 * den + s2;
      mx = ms;
    }
  }
}

extern "C" void kernel_launch(void* const* d_in, const int* in_sizes, int n_in,
                              void* d_out, int out_size, void* d_ws, size_t ws_size,
                              hipStream_t stream)
{
  const float* x  = (const float*)d_in[0];
  const float* wk = (const float*)d_in[1];
  const float* wv = (const float*)d_in[2];
  const float* wr = (const float*)d_in[3];
  const float* wo = (const float*)d_in[4];
  const float* td = (const float*)d_in[5];
  const float* tf = (const float*)d_in[6];
  const float* mk = (const float*)d_in[7];
  const float* mv = (const float*)d_in[8];
  const float* mr = (const float*)d_in[9];

  const int B = 8, T = 2048, C = 1024;
  const int M = B * T;      // 16384
  const int NC = 32, L = 64;
  const size_t MB = 1024 * 1024;

  char* ws = (char*)d_ws;
  unsigned short* mixbuf = (unsigned short*)(ws);              // 32 MiB
  unsigned short* kb     = (unsigned short*)(ws + 32 * MB);    // 32 MiB
  unsigned short* vb     = (unsigned short*)(ws + 64 * MB);    // 32 MiB
  unsigned short* rsig   = (unsigned short*)(ws + 96 * MB);    // 32 MiB
  unsigned short* wkb    = (unsigned short*)(ws + 128 * MB);   // 2 MiB each
  unsigned short* wvb    = (unsigned short*)(ws + 130 * MB);
  unsigned short* wrb    = (unsigned short*)(ws + 132 * MB);
  unsigned short* wob    = (unsigned short*)(ws + 134 * MB);
  float* snum = (float*)(ws + 136 * MB);                       // 1 MiB each
  float* sden = (float*)(ws + 137 * MB);
  float* smx  = (float*)(ws + 138 * MB);
  float* inum = (float*)(ws + 139 * MB);
  float* iden = (float*)(ws + 140 * MB);
  float* imx  = (float*)(ws + 141 * MB);
  unsigned short* rwkv = mixbuf;  // mixbuf dead by the time pass3 runs

  dim3 gGemm(M / 128, C / 128);
  int mixBlocks = (M * C / 8) / 256;
  int scanBlocks = (B * C * NC) / 256;  // 1024

  wconv_kernel<<<4096, 256, 0, stream>>>(wk, wv, wr, wo, wkb, wvb, wrb, wob);
  mix_kernel<<<mixBlocks, 256, 0, stream>>>(x, mk, mixbuf, T, C);
  gemm_bt<GM_B16><<<gGemm, 256, 0, stream>>>(mixbuf, wkb, kb, M, C, C);
  mix_kernel<<<mixBlocks, 256, 0, stream>>>(x, mv, mixbuf, T, C);
  gemm_bt<GM_B16><<<gGemm, 256, 0, stream>>>(mixbuf, wvb, vb, M, C, C);
  mix_kernel<<<mixBlocks, 256, 0, stream>>>(x, mr, mixbuf, T, C);
  gemm_bt<GM_SIG><<<gGemm, 256, 0, stream>>>(mixbuf, wrb, rsig, M, C, C);
  wkv_pass1<<<scanBlocks, 256, 0, stream>>>(kb, vb, td, snum, sden, smx, T, C, L);
  wkv_pass2<<<(B * C) / 64, 64, 0, stream>>>(snum, sden, smx, td, inum, iden, imx, L);
  wkv_pass3<<<scanBlocks, 256, 0, stream>>>(kb, vb, rsig, td, tf, inum, iden, imx,
                                            rwkv, T, C, L);
  gemm_bt<GM_F32><<<gGemm, 256, 0, stream>>>(rwkv, wob, (float*)d_out, M, C, C);
}

// Round 4
// 417.783 us; speedup vs baseline: 5.4405x; 1.0940x over previous
//
#include <hip/hip_runtime.h>
#include <stdint.h>

// RWKV TimeMixing on gfx950. I/O dtype: float32 (per reference).
// Internal: bf16 for MFMA GEMMs + k/v/rsig storage, f32 for WKV scan state.
// GEMM staging via global_load_lds width=16 (m97 structure, ~874 TF class).
// WKV: chunked associative scan (NC=32 chunks of L=64), 3 passes.
// Workspace layout (142 MiB), with buffer reuse:
//   [0,32M)     bufK bf16 (mix_k)  -> later rsig? no: rsig=bufV, rwkv=bufR
//   [32M,64M)   bufV bf16 (mix_v); after gemm_v dead -> rsig lives here
//   [64M,96M)   bufR bf16 (mix_r); after gemm_r dead -> rwkv lives here
//   [96M,128M)  kb bf16 ; vb bf16 lives in bufK after gemm_k consumed it? see launch
//   [128M,136M) wk/wv/wr/wo bf16 (2 MiB each)
//   [136M,142M) scan scratch: snum,sden,smx,inum,iden,imx (1 MiB each)

using bf16x8 = __attribute__((ext_vector_type(8))) __bf16;
using f32x4  = __attribute__((ext_vector_type(4))) float;

union FU { float f; unsigned int u; };

__device__ __forceinline__ unsigned short f2b(float f) {
  FU v; v.f = f;
  unsigned int u = v.u;
  return (unsigned short)((u + 0x7fffu + ((u >> 16) & 1u)) >> 16);
}
__device__ __forceinline__ float b2f(unsigned short h) {
  FU v; v.u = ((unsigned int)h) << 16; return v.f;
}

__device__ __forceinline__ void gl_lds16(const unsigned short* g,
                                         const unsigned short* l) {
  __builtin_amdgcn_global_load_lds(
      (const __attribute__((address_space(1))) void*)g,
      (__attribute__((address_space(3))) void*)l, 16, 0, 0);
}

// ---------------- weight f32 -> bf16 convert (4 matrices of 1M elems) -----
__global__ __launch_bounds__(256) void wconv_kernel(
    const float* __restrict__ w0, const float* __restrict__ w1,
    const float* __restrict__ w2, const float* __restrict__ w3,
    unsigned short* __restrict__ o0, unsigned short* __restrict__ o1,
    unsigned short* __restrict__ o2, unsigned short* __restrict__ o3)
{
  int b = blockIdx.x;            // 4096 blocks; 1024 per matrix
  int mat = b >> 10, blk = b & 1023;
  const float* src = (mat == 0) ? w0 : (mat == 1) ? w1 : (mat == 2) ? w2 : w3;
  unsigned short* dst = (mat == 0) ? o0 : (mat == 1) ? o1 : (mat == 2) ? o2 : o3;
  int i = blk * 1024 + threadIdx.x * 4;
  float4 v = *(const float4*)(src + i);
  union { int2 i2; unsigned short u[4]; } o;
  o.u[0] = f2b(v.x); o.u[1] = f2b(v.y); o.u[2] = f2b(v.z); o.u[3] = f2b(v.w);
  *(int2*)(dst + i) = o.i2;
}

// ------------- mix3: all three mixes in one pass over x -------------
__global__ __launch_bounds__(256) void mix3_kernel(
    const float* __restrict__ x,
    const float* __restrict__ mk, const float* __restrict__ mv,
    const float* __restrict__ mr,
    unsigned short* __restrict__ ok, unsigned short* __restrict__ ov,
    unsigned short* __restrict__ orr, int T, int C)
{
  int i = blockIdx.x * 256 + threadIdx.x;
  int base = i * 8;
  int row = base / C;          // b*T + t
  int t = row - (row / T) * T; // t within batch
  int c = base - row * C;
  float xv[8], pv[8];
  *(float4*)&xv[0] = *(const float4*)(x + base);
  *(float4*)&xv[4] = *(const float4*)(x + base + 4);
  if (t > 0) {
    *(float4*)&pv[0] = *(const float4*)(x + base - C);
    *(float4*)&pv[4] = *(const float4*)(x + base - C + 4);
  } else {
#pragma unroll
    for (int e = 0; e < 8; ++e) pv[e] = 0.f;
  }
  float mkv[8], mvv[8], mrv[8];
  *(float4*)&mkv[0] = *(const float4*)(mk + c);
  *(float4*)&mkv[4] = *(const float4*)(mk + c + 4);
  *(float4*)&mvv[0] = *(const float4*)(mv + c);
  *(float4*)&mvv[4] = *(const float4*)(mv + c + 4);
  *(float4*)&mrv[0] = *(const float4*)(mr + c);
  *(float4*)&mrv[4] = *(const float4*)(mr + c + 4);
  union { int4 i4; unsigned short u[8]; } a, b2, d;
#pragma unroll
  for (int e = 0; e < 8; ++e) {
    float xe = xv[e], pe = pv[e];
    a.u[e]  = f2b(xe * mkv[e] + pe * (1.f - mkv[e]));
    b2.u[e] = f2b(xe * mvv[e] + pe * (1.f - mvv[e]));
    d.u[e]  = f2b(xe * mrv[e] + pe * (1.f - mrv[e]));
  }
  *(int4*)(ok + base)  = a.i4;
  *(int4*)(ov + base)  = b2.i4;
  *(int4*)(orr + base) = d.i4;
}

// ---------------- GEMM: out[m,n] = sum_k A[m,k]*W[n,k] ----------------
// global_load_lds width-16 staging (m97 structure). 128x128 tile, BK=32,
// 4 waves (2x2), each wave 4x4 tiles of mfma 16x16x32 bf16.
#define GM_F32 0   // float* out
#define GM_SIG 1   // bf16 sigmoid out
#define GM_B16 2   // bf16 out

template<int MODE>
__global__ __launch_bounds__(256) void gemm_bt(
    const unsigned short* __restrict__ A,
    const unsigned short* __restrict__ W,
    void* __restrict__ outp, int M, int N, int K)
{
  __shared__ __align__(16) unsigned short As[128 * 32];
  __shared__ __align__(16) unsigned short Bs[128 * 32];
  const int tid  = threadIdx.x;
  const int lane = tid & 63;
  const int w    = tid >> 6;
  const int wm   = w >> 1, wn = w & 1;
  const int col  = lane & 15, quad = lane >> 4;
  const int mBlk = blockIdx.x * 128, nBlk = blockIdx.y * 128;

  // async staging: wave w moves strips 2w, 2w+1 (16 rows x 32 cols = 1 KiB)
  // lane l covers row s*16 + (l>>2), cols (l&3)*8 .. +8.
  const int s0 = 2 * w, s1 = 2 * w + 1;
  const int rA0 = s0 * 16 + (lane >> 2), rA1 = s1 * 16 + (lane >> 2);
  const int kc  = (lane & 3) * 8;

  const f32x4 zero = {0.f, 0.f, 0.f, 0.f};
  f32x4 acc[4][4];
#pragma unroll
  for (int i = 0; i < 4; ++i)
#pragma unroll
    for (int j = 0; j < 4; ++j) acc[i][j] = zero;

  const unsigned short* Ab = A + (size_t)mBlk * K;
  const unsigned short* Wb = W + (size_t)nBlk * K;
  const unsigned short* gA0 = Ab + (size_t)rA0 * K + kc;
  const unsigned short* gA1 = Ab + (size_t)rA1 * K + kc;
  const unsigned short* gB0 = Wb + (size_t)rA0 * K + kc;
  const unsigned short* gB1 = Wb + (size_t)rA1 * K + kc;
  const unsigned short* lA0 = &As[s0 * 512];
  const unsigned short* lA1 = &As[s1 * 512];
  const unsigned short* lB0 = &Bs[s0 * 512];
  const unsigned short* lB1 = &Bs[s1 * 512];

  for (int k0 = 0; k0 < K; k0 += 32) {
    gl_lds16(gA0 + k0, lA0);
    gl_lds16(gA1 + k0, lA1);
    gl_lds16(gB0 + k0, lB0);
    gl_lds16(gB1 + k0, lB1);
    __syncthreads();

    bf16x8 af[4], bg[4];
#pragma unroll
    for (int i = 0; i < 4; ++i)
      af[i] = *(const bf16x8*)&As[(wm * 64 + i * 16 + col) * 32 + quad * 8];
#pragma unroll
    for (int j = 0; j < 4; ++j)
      bg[j] = *(const bf16x8*)&Bs[(wn * 64 + j * 16 + col) * 32 + quad * 8];
#pragma unroll
    for (int i = 0; i < 4; ++i)
#pragma unroll
      for (int j = 0; j < 4; ++j)
        acc[i][j] = __builtin_amdgcn_mfma_f32_16x16x32_bf16(af[i], bg[j], acc[i][j], 0, 0, 0);

    __syncthreads();
  }

  // epilogue: C/D layout col=lane&15, row=quad*4+reg (m89/m91-verified)
  const int mBase = mBlk + wm * 64, nBase = nBlk + wn * 64;
#pragma unroll
  for (int i = 0; i < 4; ++i) {
#pragma unroll
    for (int j = 0; j < 4; ++j) {
#pragma unroll
      for (int r = 0; r < 4; ++r) {
        int rg = mBase + i * 16 + quad * 4 + r;
        int cg = nBase + j * 16 + col;
        float v = acc[i][j][r];
        if (MODE == GM_F32) {
          ((float*)outp)[(size_t)rg * N + cg] = v;
        } else if (MODE == GM_SIG) {
          float s = 1.0f / (1.0f + __expf(-v));
          ((unsigned short*)outp)[(size_t)rg * N + cg] = f2b(s);
        } else {
          ((unsigned short*)outp)[(size_t)rg * N + cg] = f2b(v);
        }
      }
    }
  }
}

// ---------------- WKV chunked scan ----------------
// Unnormalized recurrence: U_t = e^w U_{t-1} + e^{k_t} v_t (num), same for den.
// Stabilized triple (num, den, mx) represents (num*e^mx, den*e^mx).
// NC=32 chunks of L=64 over T=2048; B*C=8192 series.

__global__ __launch_bounds__(256) void wkv_pass1(
    const unsigned short* __restrict__ kb, const unsigned short* __restrict__ vb,
    const float* __restrict__ td,
    float* __restrict__ snum, float* __restrict__ sden, float* __restrict__ smx,
    int T, int C, int L)
{
  int g = blockIdx.x * 256 + threadIdx.x;  // 0..B*C*NC-1
  int bc = g & 8191;
  int ch = g >> 13;
  int c = bc & 1023;
  float w = -__expf(td[c]);
  float num = 0.f, den = 0.f, mx = -1e38f;
  size_t base = ((size_t)(bc >> 10) * T + (size_t)ch * L) * C + c;
  for (int j0 = 0; j0 < L; j0 += 8) {
    float kq[8], vq[8];
#pragma unroll
    for (int j = 0; j < 8; ++j) {
      size_t a = base + (size_t)(j0 + j) * C;
      kq[j] = b2f(kb[a]);
      vq[j] = b2f(vb[a]);
    }
#pragma unroll
    for (int j = 0; j < 8; ++j) {
      float k = kq[j], v = vq[j];
      float mw = mx + w;
      float ms = fmaxf(mw, k);
      float s1 = __expf(mw - ms);
      float s2 = __expf(k - ms);
      num = s1 * num + s2 * v;
      den = s1 * den + s2;
      mx = ms;
    }
  }
  int idx = ch * 8192 + bc;
  snum[idx] = num; sden[idx] = den; smx[idx] = mx;
}

__global__ __launch_bounds__(64) void wkv_pass2(
    const float* __restrict__ snum, const float* __restrict__ sden,
    const float* __restrict__ smx, const float* __restrict__ td,
    float* __restrict__ inum, float* __restrict__ iden, float* __restrict__ imx,
    int L)
{
  int bc = blockIdx.x * 64 + threadIdx.x;  // 0..8191
  int c = bc & 1023;
  float Wl = -__expf(td[c]) * (float)L;
  float num = 0.f, den = 0.f, mx = -1e38f;
#pragma unroll
  for (int ch = 0; ch < 32; ++ch) {
    int idx = ch * 8192 + bc;
    inum[idx] = num; iden[idx] = den; imx[idx] = mx;
    float sn = snum[idx], sd = sden[idx], sm = smx[idx];
    float mi = mx + Wl;
    float mo = fmaxf(mi, sm);
    float e1 = __expf(mi - mo);
    float e2 = __expf(sm - mo);
    num = e1 * num + e2 * sn;
    den = e1 * den + e2 * sd;
    mx = mo;
  }
}

__global__ __launch_bounds__(256) void wkv_pass3(
    const unsigned short* __restrict__ kb, const unsigned short* __restrict__ vb,
    const unsigned short* __restrict__ rsig,
    const float* __restrict__ td, const float* __restrict__ tf,
    const float* __restrict__ inum, const float* __restrict__ iden,
    const float* __restrict__ imx,
    unsigned short* __restrict__ rwkv, int T, int C, int L)
{
  int g = blockIdx.x * 256 + threadIdx.x;
  int bc = g & 8191;
  int ch = g >> 13;
  int c = bc & 1023;
  float w = -__expf(td[c]);
  float u = tf[c];
  int idx = ch * 8192 + bc;
  float num = inum[idx], den = iden[idx], mx = imx[idx];
  size_t base = ((size_t)(bc >> 10) * T + (size_t)ch * L) * C + c;
  for (int j0 = 0; j0 < L; j0 += 8) {
    float kq[8], vq[8], rq[8];
#pragma unroll
    for (int j = 0; j < 8; ++j) {
      size_t a = base + (size_t)(j0 + j) * C;
      kq[j] = b2f(kb[a]);
      vq[j] = b2f(vb[a]);
      rq[j] = b2f(rsig[a]);
    }
#pragma unroll
    for (int j = 0; j < 8; ++j) {
      float k = kq[j], v = vq[j];
      float ku = k + u;
      float mo = fmaxf(mx, ku);
      float e1 = __expf(mx - mo);
      float e2 = __expf(ku - mo);
      float o = (e1 * num + e2 * v) / (e1 * den + e2);
      rwkv[base + (size_t)(j0 + j) * C] = f2b(rq[j] * o);
      float mw = mx + w;
      float ms = fmaxf(mw, k);
      float s1 = __expf(mw - ms);
      float s2 = __expf(k - ms);
      num = s1 * num + s2 * v;
      den = s1 * den + s2;
      mx = ms;
    }
  }
}

extern "C" void kernel_launch(void* const* d_in, const int* in_sizes, int n_in,
                              void* d_out, int out_size, void* d_ws, size_t ws_size,
                              hipStream_t stream)
{
  const float* x  = (const float*)d_in[0];
  const float* wk = (const float*)d_in[1];
  const float* wv = (const float*)d_in[2];
  const float* wr = (const float*)d_in[3];
  const float* wo = (const float*)d_in[4];
  const float* td = (const float*)d_in[5];
  const float* tf = (const float*)d_in[6];
  const float* mk = (const float*)d_in[7];
  const float* mv = (const float*)d_in[8];
  const float* mr = (const float*)d_in[9];

  const int B = 8, T = 2048, C = 1024;
  const int M = B * T;      // 16384
  const int NC = 32, L = 64;
  const size_t MB = 1024 * 1024;

  char* ws = (char*)d_ws;
  unsigned short* bufK = (unsigned short*)(ws);              // 32 MiB
  unsigned short* bufV = (unsigned short*)(ws + 32 * MB);    // 32 MiB
  unsigned short* bufR = (unsigned short*)(ws + 64 * MB);    // 32 MiB
  unsigned short* kb   = (unsigned short*)(ws + 96 * MB);    // 32 MiB
  unsigned short* wkb  = (unsigned short*)(ws + 128 * MB);   // 2 MiB each
  unsigned short* wvb  = (unsigned short*)(ws + 130 * MB);
  unsigned short* wrb  = (unsigned short*)(ws + 132 * MB);
  unsigned short* wob  = (unsigned short*)(ws + 134 * MB);
  float* snum = (float*)(ws + 136 * MB);                     // 1 MiB each
  float* sden = (float*)(ws + 137 * MB);
  float* smx  = (float*)(ws + 138 * MB);
  float* inum = (float*)(ws + 139 * MB);
  float* iden = (float*)(ws + 140 * MB);
  float* imx  = (float*)(ws + 141 * MB);
  // buffer reuse after each producer GEMM consumes its mix input:
  unsigned short* vb   = bufK;  // written by gemm_v (bufK dead after gemm_k)
  unsigned short* rsig = bufV;  // written by gemm_r (bufV dead after gemm_v)
  unsigned short* rwkv = bufR;  // written by pass3  (bufR dead after gemm_r)

  dim3 gGemm(M / 128, C / 128);
  int mixBlocks = (M * C / 8) / 256;
  int scanBlocks = (B * C * NC) / 256;  // 1024

  wconv_kernel<<<4096, 256, 0, stream>>>(wk, wv, wr, wo, wkb, wvb, wrb, wob);
  mix3_kernel<<<mixBlocks, 256, 0, stream>>>(x, mk, mv, mr, bufK, bufV, bufR, T, C);
  gemm_bt<GM_B16><<<gGemm, 256, 0, stream>>>(bufK, wkb, kb, M, C, C);
  gemm_bt<GM_B16><<<gGemm, 256, 0, stream>>>(bufV, wvb, vb, M, C, C);
  gemm_bt<GM_SIG><<<gGemm, 256, 0, stream>>>(bufR, wrb, rsig, M, C, C);
  wkv_pass1<<<scanBlocks, 256, 0, stream>>>(kb, vb, td, snum, sden, smx, T, C, L);
  wkv_pass2<<<(B * C) / 64, 64, 0, stream>>>(snum, sden, smx, td, inum, iden, imx, L);
  wkv_pass3<<<scanBlocks, 256, 0, stream>>>(kb, vb, rsig, td, tf, inum, iden, imx,
                                            rwkv, T, C, L);
  gemm_bt<GM_F32><<<gGemm, 256, 0, stream>>>(rwkv, wob, (float*)d_out, M, C, C);
}

// Round 5
// 394.514 us; speedup vs baseline: 5.7614x; 1.0590x over previous
//
#include <hip/hip_runtime.h>
#include <stdint.h>

// RWKV TimeMixing on gfx950. I/O dtype: float32 (per reference).
// Internal: bf16 for MFMA GEMMs + k/v/rsig storage, f32 for WKV scan state.
// R4: fused prep (wconv+mix3), fused K/V projection GEMM (grid.z=2),
// R-projection GEMM with sigmoid (writes over bufK, dead by then).
// Launches: prep, gemmKV, gemmR, pass1, pass2, pass3, gemmO (7 total).
// Workspace layout (176 MiB):
//   [0,32M)     bufK bf16 (mix_k); rsig written here after gemmKV
//   [32M,64M)   bufV bf16 (mix_v)
//   [64M,96M)   bufR bf16 (mix_r); rwkv written here after gemmR
//   [96M,128M)  kb bf16
//   [128M,136M) wk/wv/wr/wo bf16 (2 MiB each)
//   [136M,142M) scan scratch: snum,sden,smx,inum,iden,imx (1 MiB each)
//   [142M,174M) vb bf16

using bf16x8 = __attribute__((ext_vector_type(8))) __bf16;
using f32x4  = __attribute__((ext_vector_type(4))) float;

union FU { float f; unsigned int u; };

__device__ __forceinline__ unsigned short f2b(float f) {
  FU v; v.f = f;
  unsigned int u = v.u;
  return (unsigned short)((u + 0x7fffu + ((u >> 16) & 1u)) >> 16);
}
__device__ __forceinline__ float b2f(unsigned short h) {
  FU v; v.u = ((unsigned int)h) << 16; return v.f;
}

__device__ __forceinline__ void gl_lds16(const unsigned short* g,
                                         const unsigned short* l) {
  __builtin_amdgcn_global_load_lds(
      (const __attribute__((address_space(1))) void*)g,
      (__attribute__((address_space(3))) void*)l, 16, 0, 0);
}

// ---------------- prep: wconv (blocks 0..4095) + mix3 (blocks 4096..12287) --
__global__ __launch_bounds__(256) void prep_kernel(
    const float* __restrict__ x,
    const float* __restrict__ w0, const float* __restrict__ w1,
    const float* __restrict__ w2, const float* __restrict__ w3,
    unsigned short* __restrict__ o0, unsigned short* __restrict__ o1,
    unsigned short* __restrict__ o2, unsigned short* __restrict__ o3,
    const float* __restrict__ mk, const float* __restrict__ mv,
    const float* __restrict__ mr,
    unsigned short* __restrict__ ok, unsigned short* __restrict__ ov,
    unsigned short* __restrict__ orr, int T, int C)
{
  int bid = blockIdx.x;
  if (bid < 4096) {
    int mat = bid >> 10, blk = bid & 1023;
    const float* src = (mat == 0) ? w0 : (mat == 1) ? w1 : (mat == 2) ? w2 : w3;
    unsigned short* dst = (mat == 0) ? o0 : (mat == 1) ? o1 : (mat == 2) ? o2 : o3;
    int i = blk * 1024 + threadIdx.x * 4;
    float4 v = *(const float4*)(src + i);
    union { int2 i2; unsigned short u[4]; } o;
    o.u[0] = f2b(v.x); o.u[1] = f2b(v.y); o.u[2] = f2b(v.z); o.u[3] = f2b(v.w);
    *(int2*)(dst + i) = o.i2;
    return;
  }
  int i = (bid - 4096) * 256 + threadIdx.x;
  int base = i * 8;
  int row = base / C;          // b*T + t
  int t = row - (row / T) * T; // t within batch
  int c = base - row * C;
  float xv[8], pv[8];
  *(float4*)&xv[0] = *(const float4*)(x + base);
  *(float4*)&xv[4] = *(const float4*)(x + base + 4);
  if (t > 0) {
    *(float4*)&pv[0] = *(const float4*)(x + base - C);
    *(float4*)&pv[4] = *(const float4*)(x + base - C + 4);
  } else {
#pragma unroll
    for (int e = 0; e < 8; ++e) pv[e] = 0.f;
  }
  float mkv[8], mvv[8], mrv[8];
  *(float4*)&mkv[0] = *(const float4*)(mk + c);
  *(float4*)&mkv[4] = *(const float4*)(mk + c + 4);
  *(float4*)&mvv[0] = *(const float4*)(mv + c);
  *(float4*)&mvv[4] = *(const float4*)(mv + c + 4);
  *(float4*)&mrv[0] = *(const float4*)(mr + c);
  *(float4*)&mrv[4] = *(const float4*)(mr + c + 4);
  union { int4 i4; unsigned short u[8]; } a, b2, d;
#pragma unroll
  for (int e = 0; e < 8; ++e) {
    float xe = xv[e], pe = pv[e];
    a.u[e]  = f2b(xe * mkv[e] + pe * (1.f - mkv[e]));
    b2.u[e] = f2b(xe * mvv[e] + pe * (1.f - mvv[e]));
    d.u[e]  = f2b(xe * mrv[e] + pe * (1.f - mrv[e]));
  }
  *(int4*)(ok + base)  = a.i4;
  *(int4*)(ov + base)  = b2.i4;
  *(int4*)(orr + base) = d.i4;
}

// ---------------- GEMM core (m97 structure) ----------------
template<typename EPI>
__device__ __forceinline__ void gemm_core(
    const unsigned short* __restrict__ A,
    const unsigned short* __restrict__ W,
    int mBlk, int nBlk, int N, int K, EPI epi)
{
  __shared__ __align__(16) unsigned short As[128 * 32];
  __shared__ __align__(16) unsigned short Bs[128 * 32];
  const int tid  = threadIdx.x;
  const int lane = tid & 63;
  const int w    = tid >> 6;
  const int wm   = w >> 1, wn = w & 1;
  const int col  = lane & 15, quad = lane >> 4;

  const int s0 = 2 * w, s1 = 2 * w + 1;
  const int rA0 = s0 * 16 + (lane >> 2), rA1 = s1 * 16 + (lane >> 2);
  const int kc  = (lane & 3) * 8;

  const f32x4 zero = {0.f, 0.f, 0.f, 0.f};
  f32x4 acc[4][4];
#pragma unroll
  for (int i = 0; i < 4; ++i)
#pragma unroll
    for (int j = 0; j < 4; ++j) acc[i][j] = zero;

  const unsigned short* Ab = A + (size_t)mBlk * K;
  const unsigned short* Wb = W + (size_t)nBlk * K;
  const unsigned short* gA0 = Ab + (size_t)rA0 * K + kc;
  const unsigned short* gA1 = Ab + (size_t)rA1 * K + kc;
  const unsigned short* gB0 = Wb + (size_t)rA0 * K + kc;
  const unsigned short* gB1 = Wb + (size_t)rA1 * K + kc;
  const unsigned short* lA0 = &As[s0 * 512];
  const unsigned short* lA1 = &As[s1 * 512];
  const unsigned short* lB0 = &Bs[s0 * 512];
  const unsigned short* lB1 = &Bs[s1 * 512];

  for (int k0 = 0; k0 < K; k0 += 32) {
    gl_lds16(gA0 + k0, lA0);
    gl_lds16(gA1 + k0, lA1);
    gl_lds16(gB0 + k0, lB0);
    gl_lds16(gB1 + k0, lB1);
    __syncthreads();

    bf16x8 af[4], bg[4];
#pragma unroll
    for (int i = 0; i < 4; ++i)
      af[i] = *(const bf16x8*)&As[(wm * 64 + i * 16 + col) * 32 + quad * 8];
#pragma unroll
    for (int j = 0; j < 4; ++j)
      bg[j] = *(const bf16x8*)&Bs[(wn * 64 + j * 16 + col) * 32 + quad * 8];
#pragma unroll
    for (int i = 0; i < 4; ++i)
#pragma unroll
      for (int j = 0; j < 4; ++j)
        acc[i][j] = __builtin_amdgcn_mfma_f32_16x16x32_bf16(af[i], bg[j], acc[i][j], 0, 0, 0);

    __syncthreads();
  }

  const int mBase = mBlk + wm * 64, nBase = nBlk + wn * 64;
#pragma unroll
  for (int i = 0; i < 4; ++i)
#pragma unroll
    for (int j = 0; j < 4; ++j)
#pragma unroll
      for (int r = 0; r < 4; ++r)
        epi(mBase + i * 16 + quad * 4 + r, nBase + j * 16 + col, acc[i][j][r]);
}

// fused K/V projection GEMM: z=0 -> kb, z=1 -> vb (both bf16, no aliasing)
__global__ __launch_bounds__(256) void gemmKV_kernel(
    const unsigned short* __restrict__ A0, const unsigned short* __restrict__ A1,
    const unsigned short* __restrict__ W0, const unsigned short* __restrict__ W1,
    unsigned short* __restrict__ out0, unsigned short* __restrict__ out1,
    int N, int K)
{
  int z = blockIdx.z;
  const unsigned short* A = (z == 0) ? A0 : A1;
  const unsigned short* W = (z == 0) ? W0 : W1;
  unsigned short* out = (z == 0) ? out0 : out1;
  gemm_core(A, W, blockIdx.x * 128, blockIdx.y * 128, N, K,
            [&](int rg, int cg, float v) {
              out[(size_t)rg * N + cg] = f2b(v);
            });
}

// R projection: sigmoid epilogue, bf16 out
__global__ __launch_bounds__(256) void gemmR_kernel(
    const unsigned short* __restrict__ A, const unsigned short* __restrict__ W,
    unsigned short* __restrict__ out, int N, int K)
{
  gemm_core(A, W, blockIdx.x * 128, blockIdx.y * 128, N, K,
            [&](int rg, int cg, float v) {
              float s = 1.0f / (1.0f + __expf(-v));
              out[(size_t)rg * N + cg] = f2b(s);
            });
}

// final GEMM: f32 output
__global__ __launch_bounds__(256) void gemmO_kernel(
    const unsigned short* __restrict__ A, const unsigned short* __restrict__ W,
    float* __restrict__ out, int N, int K)
{
  gemm_core(A, W, blockIdx.x * 128, blockIdx.y * 128, N, K,
            [&](int rg, int cg, float v) {
              out[(size_t)rg * N + cg] = v;
            });
}

// ---------------- WKV chunked scan (NC=32 chunks of L=64) ----------------
__global__ __launch_bounds__(256) void wkv_pass1(
    const unsigned short* __restrict__ kb, const unsigned short* __restrict__ vb,
    const float* __restrict__ td,
    float* __restrict__ snum, float* __restrict__ sden, float* __restrict__ smx,
    int T, int C, int L)
{
  int g = blockIdx.x * 256 + threadIdx.x;
  int bc = g & 8191;
  int ch = g >> 13;
  int c = bc & 1023;
  float w = -__expf(td[c]);
  float num = 0.f, den = 0.f, mx = -1e38f;
  size_t base = ((size_t)(bc >> 10) * T + (size_t)ch * L) * C + c;
  for (int j0 = 0; j0 < L; j0 += 8) {
    float kq[8], vq[8];
#pragma unroll
    for (int j = 0; j < 8; ++j) {
      size_t a = base + (size_t)(j0 + j) * C;
      kq[j] = b2f(kb[a]);
      vq[j] = b2f(vb[a]);
    }
#pragma unroll
    for (int j = 0; j < 8; ++j) {
      float k = kq[j], v = vq[j];
      float mw = mx + w;
      float ms = fmaxf(mw, k);
      float s1 = __expf(mw - ms);
      float s2 = __expf(k - ms);
      num = s1 * num + s2 * v;
      den = s1 * den + s2;
      mx = ms;
    }
  }
  int idx = ch * 8192 + bc;
  snum[idx] = num; sden[idx] = den; smx[idx] = mx;
}

__global__ __launch_bounds__(64) void wkv_pass2(
    const float* __restrict__ snum, const float* __restrict__ sden,
    const float* __restrict__ smx, const float* __restrict__ td,
    float* __restrict__ inum, float* __restrict__ iden, float* __restrict__ imx,
    int L)
{
  int bc = blockIdx.x * 64 + threadIdx.x;
  int c = bc & 1023;
  float Wl = -__expf(td[c]) * (float)L;
  float num = 0.f, den = 0.f, mx = -1e38f;
#pragma unroll
  for (int ch = 0; ch < 32; ++ch) {
    int idx = ch * 8192 + bc;
    inum[idx] = num; iden[idx] = den; imx[idx] = mx;
    float sn = snum[idx], sd = sden[idx], sm = smx[idx];
    float mi = mx + Wl;
    float mo = fmaxf(mi, sm);
    float e1 = __expf(mi - mo);
    float e2 = __expf(sm - mo);
    num = e1 * num + e2 * sn;
    den = e1 * den + e2 * sd;
    mx = mo;
  }
}

__global__ __launch_bounds__(256) void wkv_pass3(
    const unsigned short* __restrict__ kb, const unsigned short* __restrict__ vb,
    const unsigned short* __restrict__ rsig,
    const float* __restrict__ td, const float* __restrict__ tf,
    const float* __restrict__ inum, const float* __restrict__ iden,
    const float* __restrict__ imx,
    unsigned short* __restrict__ rwkv, int T, int C, int L)
{
  int g = blockIdx.x * 256 + threadIdx.x;
  int bc = g & 8191;
  int ch = g >> 13;
  int c = bc & 1023;
  float w = -__expf(td[c]);
  float u = tf[c];
  int idx = ch * 8192 + bc;
  float num = inum[idx], den = iden[idx], mx = imx[idx];
  size_t base = ((size_t)(bc >> 10) * T + (size_t)ch * L) * C + c;
  for (int j0 = 0; j0 < L; j0 += 8) {
    float kq[8], vq[8], rq[8];
#pragma unroll
    for (int j = 0; j < 8; ++j) {
      size_t a = base + (size_t)(j0 + j) * C;
      kq[j] = b2f(kb[a]);
      vq[j] = b2f(vb[a]);
      rq[j] = b2f(rsig[a]);
    }
#pragma unroll
    for (int j = 0; j < 8; ++j) {
      float k = kq[j], v = vq[j];
      float ku = k + u;
      float mo = fmaxf(mx, ku);
      float e1 = __expf(mx - mo);
      float e2 = __expf(ku - mo);
      float o = (e1 * num + e2 * v) / (e1 * den + e2);
      rwkv[base + (size_t)(j0 + j) * C] = f2b(rq[j] * o);
      float mw = mx + w;
      float ms = fmaxf(mw, k);
      float s1 = __expf(mw - ms);
      float s2 = __expf(k - ms);
      num = s1 * num + s2 * v;
      den = s1 * den + s2;
      mx = ms;
    }
  }
}

extern "C" void kernel_launch(void* const* d_in, const int* in_sizes, int n_in,
                              void* d_out, int out_size, void* d_ws, size_t ws_size,
                              hipStream_t stream)
{
  const float* x  = (const float*)d_in[0];
  const float* wk = (const float*)d_in[1];
  const float* wv = (const float*)d_in[2];
  const float* wr = (const float*)d_in[3];
  const float* wo = (const float*)d_in[4];
  const float* td = (const float*)d_in[5];
  const float* tf = (const float*)d_in[6];
  const float* mk = (const float*)d_in[7];
  const float* mv = (const float*)d_in[8];
  const float* mr = (const float*)d_in[9];

  const int B = 8, T = 2048, C = 1024;
  const int M = B * T;      // 16384
  const int NC = 32, L = 64;
  const size_t MB = 1024 * 1024;

  char* ws = (char*)d_ws;
  unsigned short* bufK = (unsigned short*)(ws);              // 32 MiB
  unsigned short* bufV = (unsigned short*)(ws + 32 * MB);    // 32 MiB
  unsigned short* bufR = (unsigned short*)(ws + 64 * MB);    // 32 MiB
  unsigned short* kb   = (unsigned short*)(ws + 96 * MB);    // 32 MiB
  unsigned short* wkb  = (unsigned short*)(ws + 128 * MB);   // 2 MiB each
  unsigned short* wvb  = (unsigned short*)(ws + 130 * MB);
  unsigned short* wrb  = (unsigned short*)(ws + 132 * MB);
  unsigned short* wob  = (unsigned short*)(ws + 134 * MB);
  float* snum = (float*)(ws + 136 * MB);                     // 1 MiB each
  float* sden = (float*)(ws + 137 * MB);
  float* smx  = (float*)(ws + 138 * MB);
  float* inum = (float*)(ws + 139 * MB);
  float* iden = (float*)(ws + 140 * MB);
  float* imx  = (float*)(ws + 141 * MB);
  unsigned short* vb   = (unsigned short*)(ws + 142 * MB);   // 32 MiB
  // reuse (strictly after producer of the region is fully consumed):
  unsigned short* rsig = bufV;  // written by gemmR; bufV dead after gemmKV
  unsigned short* rwkv = bufR;  // written by pass3; bufR dead after gemmR

  dim3 gGemm(M / 128, C / 128);
  dim3 gGemmKV(M / 128, C / 128, 2);
  int scanBlocks = (B * C * NC) / 256;  // 1024

  prep_kernel<<<12288, 256, 0, stream>>>(x, wk, wv, wr, wo, wkb, wvb, wrb, wob,
                                         mk, mv, mr, bufK, bufV, bufR, T, C);
  gemmKV_kernel<<<gGemmKV, 256, 0, stream>>>(bufK, bufV, wkb, wvb, kb, vb, C, C);
  gemmR_kernel<<<gGemm, 256, 0, stream>>>(bufR, wrb, rsig, C, C);
  wkv_pass1<<<scanBlocks, 256, 0, stream>>>(kb, vb, td, snum, sden, smx, T, C, L);
  wkv_pass2<<<(B * C) / 64, 64, 0, stream>>>(snum, sden, smx, td, inum, iden, imx, L);
  wkv_pass3<<<scanBlocks, 256, 0, stream>>>(kb, vb, rsig, td, tf, inum, iden, imx,
                                            rwkv, T, C, L);
  gemmO_kernel<<<gGemm, 256, 0, stream>>>(rwkv, wob, (float*)d_out, C, C);
}